// Round 24
// baseline (150.305 us; speedup 1.0000x reference)
//
#include <hip/hip_runtime.h>
#include <hip/hip_fp16.h>

#define EPSV 1e-5f
#define HSZ 6400   // max nodes per bin (N=50000/8 ~ 6252) for LDS histograms/cursors
#define BPB 32     // blocks per bin for count/fill

using half8 = __attribute__((ext_vector_type(8))) _Float16;
using f32x4 = __attribute__((ext_vector_type(4))) float;

__device__ __forceinline__ int bin_lo(int b, int mul) {
    return (int)((((long long)b << 25) + mul - 1) / mul);
}

// ---------------- fused setup: W frag split + BN consts + zero bcur ----------------
__global__ __launch_bounds__(128) void k_setup(const float* __restrict__ W1, const float* __restrict__ W2,
                                               _Float16* __restrict__ whi1, _Float16* __restrict__ wlo1,
                                               _Float16* __restrict__ whi2, _Float16* __restrict__ wlo2,
                                               const float* __restrict__ g1, const float* __restrict__ v1,
                                               const float* __restrict__ b1, const float* __restrict__ m1,
                                               const float* __restrict__ be1,
                                               const float* __restrict__ g2, const float* __restrict__ v2,
                                               const float* __restrict__ b2, const float* __restrict__ m2,
                                               const float* __restrict__ be2,
                                               float* __restrict__ par, int* __restrict__ bcur) {
    int b = blockIdx.x;
    int t = threadIdx.x;
    if (b < 32) {
        const float* W = (b < 16) ? W1 : W2;
        _Float16* whi = (b < 16) ? whi1 : whi2;
        _Float16* wlo = (b < 16) ? wlo1 : wlo2;
        int tile = ((b & 15) << 1) | (t >> 6);  // 0..31
        int l = t & 63;
        int kt = tile >> 3, ct = tile & 7;
        int k0 = kt * 32 + (l >> 4) * 8;
        int c = ct * 16 + (l & 15);
        half8 hi, lo;
#pragma unroll
        for (int j = 0; j < 8; j++) {
            float w = W[(k0 + j) * 128 + c];
            _Float16 h = (_Float16)w;
            hi[j] = h;
            lo[j] = (_Float16)(w - (float)h);
        }
        size_t o = (size_t)tile * 64 + l;
        ((half8*)whi)[o] = hi;
        ((half8*)wlo)[o] = lo;
    } else {
        int c = t;  // 0..127
        float s1 = g1[c] * rsqrtf(v1[c] + EPSV);
        par[c] = s1;
        par[128 + c] = fmaf(b1[c] - m1[c], s1, be1[c]);
        float s2 = g2[c] * rsqrtf(v2[c] + EPSV);
        par[256 + c] = s2;
        par[384 + c] = fmaf(b2[c] - m2[c], s2, be2[c]);
        if (c < 8) bcur[c] = 0;
    }
}

// ---------------- bin body: bin edges by dst range ----------------
__device__ __forceinline__ void bin_body(const int* __restrict__ src, const int* __restrict__ dst,
                                         int* __restrict__ bcur, unsigned int* __restrict__ binned,
                                         int E, int mul, int bin_cap, int bid, int nblocks, int tid) {
    int lane = tid & 63;
    int gw = (bid * 256 + tid) >> 6;
    int nw = (nblocks * 256) >> 6;
    bool v4 = ((E & 3) == 0);
    for (int base = gw * 1024; base < E; base += nw * 1024) {
        unsigned int vals[16];
        int bins[16];
        unsigned long long clo = 0, chi = 0;
#pragma unroll
        for (int g = 0; g < 4; g++) {
            int e0 = base + g * 256 + lane * 4;
            int4 s4, d4;
            if (v4 && e0 + 3 < E) {
                s4 = *(const int4*)(src + e0);
                d4 = *(const int4*)(dst + e0);
            } else {
                s4.x = (e0 < E) ? src[e0] : 0;         d4.x = (e0 < E) ? dst[e0] : -1;
                s4.y = (e0 + 1 < E) ? src[e0 + 1] : 0; d4.y = (e0 + 1 < E) ? dst[e0 + 1] : -1;
                s4.z = (e0 + 2 < E) ? src[e0 + 2] : 0; d4.z = (e0 + 2 < E) ? dst[e0 + 2] : -1;
                s4.w = (e0 + 3 < E) ? src[e0 + 3] : 0; d4.w = (e0 + 3 < E) ? dst[e0 + 3] : -1;
            }
            int ss[4] = {s4.x, s4.y, s4.z, s4.w};
            int dd[4] = {d4.x, d4.y, d4.z, d4.w};
#pragma unroll
            for (int k = 0; k < 4; k++) {
                int j = g * 4 + k;
                int d = dd[k];
                if (d >= 0) {
                    vals[j] = ((unsigned int)ss[k] << 16) | (unsigned int)d;
                    int b = (d * mul) >> 25;
                    bins[j] = b;
                    if (b < 4) clo += 1ull << (b * 16);
                    else       chi += 1ull << ((b - 4) * 16);
                } else bins[j] = -1;
            }
        }
        unsigned long long ilo = clo, ihi = chi;
#pragma unroll
        for (int d = 1; d < 64; d <<= 1) {
            unsigned long long ulo = __shfl_up(ilo, d, 64);
            unsigned long long uhi = __shfl_up(ihi, d, 64);
            if (lane >= d) { ilo += ulo; ihi += uhi; }
        }
        unsigned long long tlo = __shfl(ilo, 63, 64), thi = __shfl(ihi, 63, 64);
        unsigned long long plo = ilo - clo, phi = ihi - chi;
        int mytot = 0;
        if (lane < 4) mytot = (int)((tlo >> (lane * 16)) & 0xffff);
        else if (lane < 8) mytot = (int)((thi >> ((lane - 4) * 16)) & 0xffff);
        int alloc = 0;
        if (lane < 8) alloc = atomicAdd(&bcur[lane], mytot);
#pragma unroll
        for (int j = 0; j < 16; j++) {
            int b = bins[j];
            int bs = (b < 0) ? 0 : b;
            int bbase = __shfl(alloc, bs, 64);
            int sh = (bs & 3) * 16;
            unsigned long long sel = (bs < 4) ? plo : phi;
            int rel = (int)((sel >> sh) & 0xffffu);
            unsigned long long inc = 1ull << sh;
            if (bs < 4) plo += inc; else phi += inc;
            if (b >= 0) binned[(size_t)bs * bin_cap + bbase + rel] = vals[j];
        }
    }
}

// ---------------- GEMM body (layer 1: A f32, 3-term, LDS-staged B): Hs = fp16(A@W1) ----------
__device__ __forceinline__ void gemm_body_f32(const float* __restrict__ A,
                                              const _Float16* __restrict__ whi,
                                              const _Float16* __restrict__ wlo,
                                              unsigned short* __restrict__ out, int M,
                                              int bid, int tid, uint4* __restrict__ sB) {
    int l = tid & 63;
    int w = tid >> 6;
    int r0 = bid * 64 + w * 16;
    int ra = r0 + (l & 15);
    if (ra >= M) ra = M - 1;
    int kl = (l >> 4) * 8;

    float4 af0[4], af1[4];
#pragma unroll
    for (int kt = 0; kt < 4; kt++) {
        const float* pa = A + (size_t)ra * 128 + kt * 32 + kl;
        af0[kt] = *(const float4*)pa;
        af1[kt] = *(const float4*)(pa + 4);
    }

    {
        const uint4* gh = (const uint4*)whi;
        const uint4* gl = (const uint4*)wlo;
#pragma unroll
        for (int i = 0; i < 8; i++) sB[tid + i * 256] = gh[tid + i * 256];
#pragma unroll
        for (int i = 0; i < 8; i++) sB[2048 + tid + i * 256] = gl[tid + i * 256];
    }
    __syncthreads();

    f32x4 acc[8];
#pragma unroll
    for (int i = 0; i < 8; i++) acc[i] = (f32x4)0.f;

    const half8* bh8 = (const half8*)sB;
    const half8* bl8 = (const half8*)(sB + 2048);

#pragma unroll
    for (int kt = 0; kt < 4; kt++) {
        half8 ah, al;
        float fa[8] = {af0[kt].x, af0[kt].y, af0[kt].z, af0[kt].w,
                       af1[kt].x, af1[kt].y, af1[kt].z, af1[kt].w};
#pragma unroll
        for (int j = 0; j < 8; j++) {
            _Float16 h = (_Float16)fa[j];
            ah[j] = h;
            al[j] = (_Float16)(fa[j] - (float)h);
        }
#pragma unroll
        for (int ct = 0; ct < 8; ct++) {
            half8 bh = bh8[(kt * 8 + ct) * 64 + l];
            half8 bl = bl8[(kt * 8 + ct) * 64 + l];
            acc[ct] = __builtin_amdgcn_mfma_f32_16x16x32_f16(ah, bh, acc[ct], 0, 0, 0);
            acc[ct] = __builtin_amdgcn_mfma_f32_16x16x32_f16(al, bh, acc[ct], 0, 0, 0);
            acc[ct] = __builtin_amdgcn_mfma_f32_16x16x32_f16(ah, bl, acc[ct], 0, 0, 0);
        }
    }

    __syncthreads();
    _Float16* stw = (_Float16*)sB + w * 2048;
#pragma unroll
    for (int r = 0; r < 4; r++) {
        int trow = (l >> 4) * 4 + r;
#pragma unroll
        for (int ct = 0; ct < 8; ct++)
            stw[trow * 128 + ct * 16 + (l & 15)] = (_Float16)(acc[ct][r]);
    }
#pragma unroll
    for (int p = 0; p < 4; p++) {
        int trow = p * 4 + (l >> 4);
        int grow = r0 + trow;
        if (grow < M) {
            uint4 v = *(const uint4*)&stw[trow * 128 + (l & 15) * 8];
            *(uint4*)&out[(size_t)grow * 128 + (l & 15) * 8] = v;
        }
    }
}

// Merged: blocks [0, bin_blocks) bin the edges; the rest run layer-1 GEMM (independent).
__global__ __launch_bounds__(256) void k_bingemm(const int* __restrict__ src, const int* __restrict__ dst,
                                                 int* __restrict__ bcur, unsigned int* __restrict__ binned,
                                                 int E, int mul, int bin_cap,
                                                 const float* __restrict__ x,
                                                 const _Float16* __restrict__ whi,
                                                 const _Float16* __restrict__ wlo,
                                                 unsigned short* __restrict__ outHs, int M, int bin_blocks) {
    __shared__ uint4 sB[4096];  // 64 KB (gemm path)
    if ((int)blockIdx.x < bin_blocks) {
        bin_body(src, dst, bcur, binned, E, mul, bin_cap, blockIdx.x, bin_blocks, threadIdx.x);
        return;
    }
    gemm_body_f32(x, whi, wlo, outHs, M, blockIdx.x - bin_blocks, threadIdx.x, sB);
}

// ---------------- Phase 2a: per-(bin,block) LDS histogram -> partial counts ----------------
__global__ __launch_bounds__(256) void k_count(const unsigned int* __restrict__ binned,
                                               const int* __restrict__ bcnt, int* __restrict__ phist,
                                               int mul, int bin_cap) {
    __shared__ int hist[HSZ];
    int b = blockIdx.x & 7;
    int blk = blockIdx.x >> 3;
    int t = threadIdx.x;
    for (int i = t; i < HSZ; i += 256) hist[i] = 0;
    __syncthreads();
    int lo = bin_lo(b, mul);
    int cnt = bcnt[b];
    int e0 = (int)((long long)blk * cnt / BPB);
    int e1 = (int)((long long)(blk + 1) * cnt / BPB);
    const unsigned int* bp = binned + (size_t)b * bin_cap;
    for (int i = e0 + t; i < e1; i += 256) {
        int d = (int)(bp[i] & 0xffffu);
        atomicAdd(&hist[d - lo], 1);
    }
    __syncthreads();
    int* ph = phist + (size_t)blockIdx.x * HSZ;
    for (int i = t; i < HSZ; i += 256) ph[i] = hist[i];
}

// ---------------- Phase 2b: deg from partials; partials -> exclusive prefixes; padded block sums ----
__global__ __launch_bounds__(256) void k_bsum(int* __restrict__ phist, int* __restrict__ deg,
                                              int* __restrict__ bsum, int N, int mul) {
    int t = threadIdx.x;
    int base = blockIdx.x * 1024;
    int s = 0;
    for (int j = 0; j < 4; j++) {
        int i = base + j * 256 + t;
        if (i < N) {
            int b = (i * mul) >> 25;
            int lo = bin_lo(b, mul);
            int local = i - lo;
            int run = 0;
#pragma unroll
            for (int blk = 0; blk < BPB; blk++) {
                int* p = phist + (size_t)(blk * 8 + b) * HSZ + local;
                int c = *p;
                *p = run;
                run += c;
            }
            deg[i] = run;
            s += (run + 7) & ~7;
        }
    }
#pragma unroll
    for (int d = 1; d < 64; d <<= 1) s += __shfl_xor(s, d, 64);
    __shared__ int ws[4];
    if ((t & 63) == 0) ws[t >> 6] = s;
    __syncthreads();
    if (t == 0) bsum[blockIdx.x] = ws[0] + ws[1] + ws[2] + ws[3];
}

// ---------------- scanout with inline top-scan: row_start (8-aligned), rend, dinv ----------------
__global__ __launch_bounds__(256) void k_scanout(const int* __restrict__ deg, const int* __restrict__ bsum,
                                                 int* __restrict__ row_start, int* __restrict__ rend,
                                                 float* __restrict__ dinv, int n, int nb) {
    __shared__ int s_boff;
    __shared__ int ws[4];
    int t = threadIdx.x, lane = t & 63, wid = t >> 6;
    if (t < 64) {
        int v = (t < nb) ? bsum[t] : 0;
        int incl = v;
#pragma unroll
        for (int d = 1; d < 64; d <<= 1) {
            int u = __shfl_up(incl, d, 64);
            if (t >= d) incl += u;
        }
        if (t == (int)blockIdx.x) s_boff = incl - v;
    }
    __syncthreads();
    int base = blockIdx.x * 1024 + t * 4;
    int v[4], pv[4], ts = 0;
#pragma unroll
    for (int j = 0; j < 4; j++) {
        v[j] = (base + j < n) ? deg[base + j] : 0;
        pv[j] = (v[j] + 7) & ~7;
        ts += pv[j];
    }
    int incl = ts;
#pragma unroll
    for (int d = 1; d < 64; d <<= 1) {
        int u = __shfl_up(incl, d, 64);
        if (lane >= d) incl += u;
    }
    if (lane == 63) ws[wid] = incl;
    __syncthreads();
    int wo = 0;
    for (int i = 0; i < wid; i++) wo += ws[i];
    int run = s_boff + wo + (incl - ts);
#pragma unroll
    for (int j = 0; j < 4; j++) {
        if (base + j < n) {
            row_start[base + j] = run;
            rend[base + j] = run + v[j];
            dinv[base + j] = rsqrtf((float)v[j] + 1.0f);
            run += pv[j];
        }
    }
}

// ---------------- Phase 2c: fill via LDS cursors; csr entry = (fp16(dinv[src])<<16) | src ----------
__global__ __launch_bounds__(256) void k_fill(const unsigned int* __restrict__ binned,
                                              const int* __restrict__ bcnt, const int* __restrict__ row_start,
                                              const int* __restrict__ phist, const float* __restrict__ dinv,
                                              unsigned int* __restrict__ csr,
                                              int N, int mul, int bin_cap) {
    __shared__ int cur[HSZ];
    int b = blockIdx.x & 7;
    int blk = blockIdx.x >> 3;
    int t = threadIdx.x;
    int lo = bin_lo(b, mul);
    int hi = (b == 7) ? N : bin_lo(b + 1, mul);
    if (hi > N) hi = N;
    const int* ph = phist + (size_t)blockIdx.x * HSZ;
    for (int i = t; i < HSZ; i += 256) {
        int d = lo + i;
        cur[i] = (d < hi) ? (row_start[d] + ph[i]) : 0;
    }
    __syncthreads();
    int cnt = bcnt[b];
    int e0 = (int)((long long)blk * cnt / BPB);
    int e1 = (int)((long long)(blk + 1) * cnt / BPB);
    const unsigned int* bp = binned + (size_t)b * bin_cap;
    for (int i = e0 + t; i < e1; i += 256) {
        unsigned int v = bp[i];
        int d = (int)(v & 0xffffu);
        int s = (int)(v >> 16);
        __half h = __float2half_rn(dinv[s]);
        unsigned short hb = *(unsigned short*)&h;
        int q = atomicAdd(&cur[d - lo], 1);   // LDS atomic
        csr[q] = ((unsigned int)hb << 16) | (unsigned int)s;
    }
}

// ---------------- weighted fp16 gather helpers ----------------
__device__ __forceinline__ void f2fma(float2& a, const __half2 h, float w) {
    float2 f = __half22float2(h);
    a.x = fmaf(f.x, w, a.x);
    a.y = fmaf(f.y, w, a.y);
}

__device__ __forceinline__ float pk_w(unsigned int pk) {
    __half h;
    *(unsigned short*)&h = (unsigned short)(pk >> 16);
    return __half2float(h);
}

// single-chunk pipeline (8 gathers in flight) — lower VGPR for the fused kernel
__device__ __forceinline__ void aggr_gather1(const float4* __restrict__ Hs4, const unsigned int* __restrict__ csr,
                                             int rs, int re, int node, float dn, int lc, float2 acc[4]) {
    {
        float4 sv = Hs4[(size_t)node * 16 + lc];
        const __half2* h = (const __half2*)&sv;
        float2 f0 = __half22float2(h[0]), f1 = __half22float2(h[1]);
        float2 f2 = __half22float2(h[2]), f3 = __half22float2(h[3]);
        acc[0] = make_float2(f0.x * dn, f0.y * dn);
        acc[1] = make_float2(f1.x * dn, f1.y * dn);
        acc[2] = make_float2(f2.x * dn, f2.y * dn);
        acc[3] = make_float2(f3.x * dn, f3.y * dn);
    }
    int nch = (re - rs + 7) >> 3;
    if (nch <= 0) return;
    float2 accB[4] = {{0.f, 0.f}, {0.f, 0.f}, {0.f, 0.f}, {0.f, 0.f}};
    const uint4* cp = (const uint4*)(csr + rs);
    uint4 q0 = cp[0], q1 = cp[1];
    for (int c = 0; c < nch; c++) {
        uint4 n0 = q0, n1 = q1;
        if (c + 1 < nch) { n0 = cp[2 * c + 2]; n1 = cp[2 * c + 3]; }
        unsigned int pks[8] = {q0.x, q0.y, q0.z, q0.w, q1.x, q1.y, q1.z, q1.w};
        int base = rs + c * 8;
        float4 v[8];
        float w[8];
#pragma unroll
        for (int j = 0; j < 8; j++) {
            unsigned int pk = (base + j < re) ? pks[j] : 0u;
            w[j] = pk_w(pk);
            v[j] = Hs4[(size_t)(pk & 0xffffu) * 16 + lc];
        }
#pragma unroll
        for (int j = 0; j < 8; j++) {
            const __half2* h = (const __half2*)&v[j];
            float2* acp = (j & 1) ? accB : acc;
            f2fma(acp[0], h[0], w[j]);
            f2fma(acp[1], h[1], w[j]);
            f2fma(acp[2], h[2], w[j]);
            f2fma(acp[3], h[3], w[j]);
        }
        q0 = n0; q1 = n1;
    }
#pragma unroll
    for (int k = 0; k < 4; k++) {
        acc[k].x += accB[k].x;
        acc[k].y += accB[k].y;
    }
}

__device__ __forceinline__ void bn_relu(const float2 acc[4], float dn, const float* __restrict__ par,
                                        int lc, float4& y0, float4& y1) {
    float4 s0 = ((const float4*)par)[lc * 2];
    float4 s1 = ((const float4*)par)[lc * 2 + 1];
    float4 t0 = ((const float4*)par)[32 + lc * 2];
    float4 t1 = ((const float4*)par)[32 + lc * 2 + 1];
    y0.x = fmaxf(fmaf(acc[0].x * dn, s0.x, t0.x), 0.f);
    y0.y = fmaxf(fmaf(acc[0].y * dn, s0.y, t0.y), 0.f);
    y0.z = fmaxf(fmaf(acc[1].x * dn, s0.z, t0.z), 0.f);
    y0.w = fmaxf(fmaf(acc[1].y * dn, s0.w, t0.w), 0.f);
    y1.x = fmaxf(fmaf(acc[2].x * dn, s1.x, t1.x), 0.f);
    y1.y = fmaxf(fmaf(acc[2].y * dn, s1.y, t1.y), 0.f);
    y1.z = fmaxf(fmaf(acc[3].x * dn, s1.z, t1.z), 0.f);
    y1.w = fmaxf(fmaf(acc[3].y * dn, s1.w, t1.w), 0.f);
}

// ---------------- FUSED: layer-1 aggregation + layer-2 GEMM (one block = 64 nodes) -------------
// LDS = 32 KB (whi frags only) + 16 KB (A in MFMA-fragment layout; reused for C) = 48 KB
// -> 2 blocks/CU guaranteed (96 KB << 160 KiB; wave-capped at 32 waves/CU).
// wlo frags are read from GLOBAL (L2-resident, 64 KB reused by all blocks) in the MFMA phase.
__global__ __launch_bounds__(1024, 4) void k_aggr_gemm(const float4* __restrict__ Hs4,
                                                       const int* __restrict__ row_start,
                                                       const int* __restrict__ rend,
                                                       const unsigned int* __restrict__ csr,
                                                       const float* __restrict__ dinv,
                                                       const float* __restrict__ par,
                                                       const _Float16* __restrict__ whi,
                                                       const _Float16* __restrict__ wlo,
                                                       unsigned short* __restrict__ outHs2, int n) {
    __shared__ uint4 sB[2048];            // 32 KB: whi fragment image only
    __shared__ _Float16 sA[64 * 128];     // 16 KB: A in fragment layout (reused for C)
    int t = threadIdx.x;

    // stage whi early (HBM/L2 latency overlaps the gather below)
    {
        const uint4* gh = (const uint4*)whi;
        sB[t] = gh[t];
        sB[t + 1024] = gh[t + 1024];
    }

    int lc = t & 15;
    int nl = t >> 4;                      // local node 0..63
    int node = blockIdx.x * 64 + nl;
    float4 y0 = make_float4(0.f, 0.f, 0.f, 0.f);
    float4 y1 = make_float4(0.f, 0.f, 0.f, 0.f);
    if (node < n) {
        float dn = dinv[node];
        float2 acc[4];
        aggr_gather1(Hs4, csr, row_start[node], rend[node], node, dn, lc, acc);
        bn_relu(acc, dn, par, lc, y0, y1);
    }
    // write A directly in MFMA fragment layout (one 16B ds_write; 16-way conflict is one-time)
    {
        half8 av;
        av[0] = (_Float16)y0.x; av[1] = (_Float16)y0.y; av[2] = (_Float16)y0.z; av[3] = (_Float16)y0.w;
        av[4] = (_Float16)y1.x; av[5] = (_Float16)y1.y; av[6] = (_Float16)y1.z; av[7] = (_Float16)y1.w;
        int tile = ((nl >> 4) << 2) | (lc >> 2);
        int fl = ((lc & 3) << 4) | (nl & 15);
        ((half8*)sA)[tile * 64 + fl] = av;
    }
    __syncthreads();

    // GEMM: wave w handles output tiles w*2, w*2+1 (tile = rt*8+ct; rt in [0,4), ct in [0,8))
    int w = t >> 6, l = t & 63;
    const half8* bh8 = (const half8*)sB;
    const half8* gl8 = (const half8*)wlo;   // global (L2-resident)
    const half8* aF = (const half8*)sA;
    f32x4 accT[2];
#pragma unroll
    for (int tt = 0; tt < 2; tt++) {
        int tile = w * 2 + tt;
        int rt = tile >> 3, ct = tile & 7;
        // preload this tile's 4 wlo frags from global (independent loads in flight)
        half8 bl[4];
#pragma unroll
        for (int kt = 0; kt < 4; kt++) bl[kt] = gl8[(kt * 8 + ct) * 64 + l];
        f32x4 acc = (f32x4)0.f;
#pragma unroll
        for (int kt = 0; kt < 4; kt++) {
            half8 a = aF[(rt * 4 + kt) * 64 + l];
            half8 bh = bh8[(kt * 8 + ct) * 64 + l];
            acc = __builtin_amdgcn_mfma_f32_16x16x32_f16(a, bh, acc, 0, 0, 0);
            acc = __builtin_amdgcn_mfma_f32_16x16x32_f16(a, bl[kt], acc, 0, 0, 0);
        }
        accT[tt] = acc;
    }
    __syncthreads();  // all A reads done; reuse sA for C (flat [64][128])

#pragma unroll
    for (int tt = 0; tt < 2; tt++) {
        int tile = w * 2 + tt;
        int rt = tile >> 3, ct = tile & 7;
#pragma unroll
        for (int r = 0; r < 4; r++) {
            int row = rt * 16 + (l >> 4) * 4 + r;
            sA[row * 128 + ct * 16 + (l & 15)] = (_Float16)(accT[tt][r]);
        }
    }
    __syncthreads();

    // coalesced store: thread t -> row t>>4, 8 channels at (t&15)*8
    {
        int row = t >> 4;
        int grow = blockIdx.x * 64 + row;
        if (grow < n) {
            uint4 v = *(const uint4*)&sA[row * 128 + (t & 15) * 8];
            *(uint4*)&outHs2[(size_t)grow * 128 + (t & 15) * 8] = v;
        }
    }
}

// ---------------- layer-2 aggregation + classifier (2-chunk pipeline gather) ----------------
__device__ __forceinline__ void aggr_gather2(const float4* __restrict__ Hs4, const unsigned int* __restrict__ csr,
                                             int rs, int re, int node, float dn, int lc, float2 acc[4]) {
    {
        float4 sv = Hs4[(size_t)node * 16 + lc];
        const __half2* h = (const __half2*)&sv;
        float2 f0 = __half22float2(h[0]), f1 = __half22float2(h[1]);
        float2 f2 = __half22float2(h[2]), f3 = __half22float2(h[3]);
        acc[0] = make_float2(f0.x * dn, f0.y * dn);
        acc[1] = make_float2(f1.x * dn, f1.y * dn);
        acc[2] = make_float2(f2.x * dn, f2.y * dn);
        acc[3] = make_float2(f3.x * dn, f3.y * dn);
    }
    int nch = (re - rs + 7) >> 3;
    if (nch <= 0) return;
    float2 accB[4] = {{0.f, 0.f}, {0.f, 0.f}, {0.f, 0.f}, {0.f, 0.f}};
    const uint4* cp = (const uint4*)(csr + rs);
    uint4 qa0 = cp[0], qa1 = cp[1];
    uint4 qb0 = cp[2], qb1 = cp[3];
    for (int c = 0; c < nch; c += 2) {
        uint4 na0 = qa0, na1 = qa1, nb0 = qb0, nb1 = qb1;
        if (c + 2 < nch) { na0 = cp[2 * c + 4]; na1 = cp[2 * c + 5]; nb0 = cp[2 * c + 6]; nb1 = cp[2 * c + 7]; }
        unsigned int pA[8] = {qa0.x, qa0.y, qa0.z, qa0.w, qa1.x, qa1.y, qa1.z, qa1.w};
        unsigned int pB[8] = {qb0.x, qb0.y, qb0.z, qb0.w, qb1.x, qb1.y, qb1.z, qb1.w};
        int baseA = rs + c * 8;
        int baseB = baseA + 8;
        float4 vA[8], vB[8];
        float wA[8], wB[8];
#pragma unroll
        for (int j = 0; j < 8; j++) {
            unsigned int pk = (baseA + j < re) ? pA[j] : 0u;
            wA[j] = pk_w(pk);
            vA[j] = Hs4[(size_t)(pk & 0xffffu) * 16 + lc];
        }
#pragma unroll
        for (int j = 0; j < 8; j++) {
            unsigned int pk = (baseB + j < re) ? pB[j] : 0u;
            wB[j] = pk_w(pk);
            vB[j] = Hs4[(size_t)(pk & 0xffffu) * 16 + lc];
        }
#pragma unroll
        for (int j = 0; j < 8; j++) {
            const __half2* h = (const __half2*)&vA[j];
            float2* acp = (j & 1) ? accB : acc;
            f2fma(acp[0], h[0], wA[j]);
            f2fma(acp[1], h[1], wA[j]);
            f2fma(acp[2], h[2], wA[j]);
            f2fma(acp[3], h[3], wA[j]);
        }
#pragma unroll
        for (int j = 0; j < 8; j++) {
            const __half2* h = (const __half2*)&vB[j];
            float2* acp = (j & 1) ? accB : acc;
            f2fma(acp[0], h[0], wB[j]);
            f2fma(acp[1], h[1], wB[j]);
            f2fma(acp[2], h[2], wB[j]);
            f2fma(acp[3], h[3], wB[j]);
        }
        qa0 = na0; qa1 = na1; qb0 = nb0; qb1 = nb1;
    }
#pragma unroll
    for (int k = 0; k < 4; k++) {
        acc[k].x += accB[k].x;
        acc[k].y += accB[k].y;
    }
}

__global__ __launch_bounds__(256) void k_aggr_cls(const float4* __restrict__ Hs4, const int* __restrict__ row_start,
                                                  const int* __restrict__ rend,
                                                  const unsigned int* __restrict__ csr, const float* __restrict__ dinv,
                                                  const float* __restrict__ par, const float4* __restrict__ Wc4,
                                                  const float* __restrict__ bc, float2* __restrict__ out, int n) {
    int lc = threadIdx.x & 15;
    int node = blockIdx.x * 16 + (threadIdx.x >> 4);
    if (node >= n) return;
    float dn = dinv[node];
    float2 acc[4];
    aggr_gather2(Hs4, csr, row_start[node], rend[node], node, dn, lc, acc);
    float4 y0, y1;
    bn_relu(acc, dn, par, lc, y0, y1);
    float4 w0 = Wc4[lc * 4], w1 = Wc4[lc * 4 + 1], w2 = Wc4[lc * 4 + 2], w3 = Wc4[lc * 4 + 3];
    float p0 = y0.x * w0.x + y0.y * w0.z + y0.z * w1.x + y0.w * w1.z
             + y1.x * w2.x + y1.y * w2.z + y1.z * w3.x + y1.w * w3.z;
    float p1 = y0.x * w0.y + y0.y * w0.w + y0.z * w1.y + y0.w * w1.w
             + y1.x * w2.y + y1.y * w2.w + y1.z * w3.y + y1.w * w3.w;
#pragma unroll
    for (int d = 1; d < 16; d <<= 1) {
        p0 += __shfl_xor(p0, d, 16);
        p1 += __shfl_xor(p1, d, 16);
    }
    if (lc == 0) out[node] = make_float2(p0 + bc[0], p1 + bc[1]);
}

extern "C" void kernel_launch(void* const* d_in, const int* in_sizes, int n_in,
                              void* d_out, int out_size, void* d_ws, size_t ws_size,
                              hipStream_t stream) {
    const float* x = (const float*)d_in[0];
    const int* ei = (const int*)d_in[1];
    const float* W1 = (const float*)d_in[2];
    const float* b1 = (const float*)d_in[3];
    const float* g1 = (const float*)d_in[4];
    const float* be1 = (const float*)d_in[5];
    const float* m1 = (const float*)d_in[6];
    const float* v1 = (const float*)d_in[7];
    const float* W2 = (const float*)d_in[8];
    const float* b2 = (const float*)d_in[9];
    const float* g2 = (const float*)d_in[10];
    const float* be2 = (const float*)d_in[11];
    const float* m2 = (const float*)d_in[12];
    const float* v2 = (const float*)d_in[13];
    const float* Wc = (const float*)d_in[14];
    const float* bc = (const float*)d_in[15];
    float* out = (float*)d_out;

    const int N = in_sizes[0] / 128;   // 50000 (< 65536: u16 packing valid; N/8 < HSZ)
    const int E = in_sizes[1] / 2;
    const int* src = ei;
    const int* dst = ei + E;

    const int mul = (int)((8LL << 25) / N);
    const int bin_cap = ((E / 8 + 8192 + 63) / 64) * 64;

    // workspace layout (int units)
    int* W = (int*)d_ws;
    size_t off = 0;
    int* deg = W + off; off += N;
    int* bcur = W + off; off += 8;
    int* row_start = W + off; off += (size_t)N + 1;
    int* rend = W + off; off += N;
    float* dinv = (float*)(W + off); off += N;
    int* bsum = W + off; off += 64;
    float* par = (float*)(W + off); off += 512;
    _Float16* whi1 = (_Float16*)(W + off); off += 8192;   // 16384 halves (32 KB)
    _Float16* wlo1 = (_Float16*)(W + off); off += 8192;
    _Float16* whi2 = (_Float16*)(W + off); off += 8192;
    _Float16* wlo2 = (_Float16*)(W + off); off += 8192;
    int* phist = W + off; off += (size_t)8 * BPB * HSZ;   // 6.5 MB (fully overwritten each call)
    unsigned int* csr = (unsigned int*)(W + off); off += (size_t)E + 8 * N + 64;  // u32 entries
    unsigned int* binned = (unsigned int*)(W + off); off += (size_t)8 * bin_cap;
    off = (off + 3) & ~(size_t)3;
    __half* Hs = (__half*)(W + off); off += (size_t)N * 64;    // N*128 halves (layer-1 GEMM out)
    __half* Hs2 = (__half*)(W + off);                          // N*128 halves (fused out)

    // setup: W frag split x2 + BN consts + zero bcur
    k_setup<<<33, 128, 0, stream>>>(W1, W2, whi1, wlo1, whi2, wlo2,
                                    g1, v1, b1, m1, be1, g2, v2, b2, m2, be2,
                                    par, bcur);

    int nb = (N + 1023) / 1024;  // <= 64
    int gbm = (N + 63) / 64;
    int bin_blocks = 512;
    // merged: edge binning overlapped with layer-1 GEMM
    k_bingemm<<<bin_blocks + gbm, 256, 0, stream>>>(src, dst, bcur, binned, E, mul, bin_cap,
                                                    x, whi1, wlo1, (unsigned short*)Hs, N, bin_blocks);
    k_count<<<8 * BPB, 256, 0, stream>>>(binned, bcur, phist, mul, bin_cap);
    k_bsum<<<nb, 256, 0, stream>>>(phist, deg, bsum, N, mul);
    k_scanout<<<nb, 256, 0, stream>>>(deg, bsum, row_start, rend, dinv, N, nb);
    k_fill<<<8 * BPB, 256, 0, stream>>>(binned, bcur, row_start, phist, dinv, csr, N, mul, bin_cap);

    // fused: layer-1 aggregation + BN/ReLU + layer-2 GEMM -> Hs2
    k_aggr_gemm<<<gbm, 1024, 0, stream>>>((const float4*)Hs, row_start, rend, csr, dinv, par,
                                          whi2, wlo2, (unsigned short*)Hs2, N);
    // layer-2 aggregation + BN/ReLU + classifier
    int ab = (N + 15) / 16;
    k_aggr_cls<<<ab, 256, 0, stream>>>((const float4*)Hs2, row_start, rend, csr, dinv, par + 256,
                                       (const float4*)Wc, bc, (float2*)out, N);
}

// Round 25
// 145.002 us; speedup vs baseline: 1.0366x; 1.0366x over previous
//
#include <hip/hip_runtime.h>
#include <hip/hip_fp16.h>

#define EPSV 1e-5f
#define HSZ 6400   // max nodes per bin (N=50000/8 ~ 6252) for LDS histograms/cursors
#define BPB 32     // blocks per bin for count/fill

using half8 = __attribute__((ext_vector_type(8))) _Float16;
using f32x4 = __attribute__((ext_vector_type(4))) float;

__device__ __forceinline__ int bin_lo(int b, int mul) {
    return (int)((((long long)b << 25) + mul - 1) / mul);
}

// ---------------- fused setup: W frag split + BN consts + zero bcur ----------------
__global__ __launch_bounds__(128) void k_setup(const float* __restrict__ W1, const float* __restrict__ W2,
                                               _Float16* __restrict__ whi1, _Float16* __restrict__ wlo1,
                                               _Float16* __restrict__ whi2, _Float16* __restrict__ wlo2,
                                               const float* __restrict__ g1, const float* __restrict__ v1,
                                               const float* __restrict__ b1, const float* __restrict__ m1,
                                               const float* __restrict__ be1,
                                               const float* __restrict__ g2, const float* __restrict__ v2,
                                               const float* __restrict__ b2, const float* __restrict__ m2,
                                               const float* __restrict__ be2,
                                               float* __restrict__ par, int* __restrict__ bcur) {
    int b = blockIdx.x;
    int t = threadIdx.x;
    if (b < 32) {
        const float* W = (b < 16) ? W1 : W2;
        _Float16* whi = (b < 16) ? whi1 : whi2;
        _Float16* wlo = (b < 16) ? wlo1 : wlo2;
        int tile = ((b & 15) << 1) | (t >> 6);  // 0..31
        int l = t & 63;
        int kt = tile >> 3, ct = tile & 7;
        int k0 = kt * 32 + (l >> 4) * 8;
        int c = ct * 16 + (l & 15);
        half8 hi, lo;
#pragma unroll
        for (int j = 0; j < 8; j++) {
            float w = W[(k0 + j) * 128 + c];
            _Float16 h = (_Float16)w;
            hi[j] = h;
            lo[j] = (_Float16)(w - (float)h);
        }
        size_t o = (size_t)tile * 64 + l;
        ((half8*)whi)[o] = hi;
        ((half8*)wlo)[o] = lo;
    } else {
        int c = t;  // 0..127
        float s1 = g1[c] * rsqrtf(v1[c] + EPSV);
        par[c] = s1;
        par[128 + c] = fmaf(b1[c] - m1[c], s1, be1[c]);
        float s2 = g2[c] * rsqrtf(v2[c] + EPSV);
        par[256 + c] = s2;
        par[384 + c] = fmaf(b2[c] - m2[c], s2, be2[c]);
        if (c < 8) bcur[c] = 0;
    }
}

// ---------------- bin body: bin edges by dst range ----------------
__device__ __forceinline__ void bin_body(const int* __restrict__ src, const int* __restrict__ dst,
                                         int* __restrict__ bcur, unsigned int* __restrict__ binned,
                                         int E, int mul, int bin_cap, int bid, int nblocks, int tid) {
    int lane = tid & 63;
    int gw = (bid * 256 + tid) >> 6;
    int nw = (nblocks * 256) >> 6;
    bool v4 = ((E & 3) == 0);
    for (int base = gw * 1024; base < E; base += nw * 1024) {
        unsigned int vals[16];
        int bins[16];
        unsigned long long clo = 0, chi = 0;
#pragma unroll
        for (int g = 0; g < 4; g++) {
            int e0 = base + g * 256 + lane * 4;
            int4 s4, d4;
            if (v4 && e0 + 3 < E) {
                s4 = *(const int4*)(src + e0);
                d4 = *(const int4*)(dst + e0);
            } else {
                s4.x = (e0 < E) ? src[e0] : 0;         d4.x = (e0 < E) ? dst[e0] : -1;
                s4.y = (e0 + 1 < E) ? src[e0 + 1] : 0; d4.y = (e0 + 1 < E) ? dst[e0 + 1] : -1;
                s4.z = (e0 + 2 < E) ? src[e0 + 2] : 0; d4.z = (e0 + 2 < E) ? dst[e0 + 2] : -1;
                s4.w = (e0 + 3 < E) ? src[e0 + 3] : 0; d4.w = (e0 + 3 < E) ? dst[e0 + 3] : -1;
            }
            int ss[4] = {s4.x, s4.y, s4.z, s4.w};
            int dd[4] = {d4.x, d4.y, d4.z, d4.w};
#pragma unroll
            for (int k = 0; k < 4; k++) {
                int j = g * 4 + k;
                int d = dd[k];
                if (d >= 0) {
                    vals[j] = ((unsigned int)ss[k] << 16) | (unsigned int)d;
                    int b = (d * mul) >> 25;
                    bins[j] = b;
                    if (b < 4) clo += 1ull << (b * 16);
                    else       chi += 1ull << ((b - 4) * 16);
                } else bins[j] = -1;
            }
        }
        unsigned long long ilo = clo, ihi = chi;
#pragma unroll
        for (int d = 1; d < 64; d <<= 1) {
            unsigned long long ulo = __shfl_up(ilo, d, 64);
            unsigned long long uhi = __shfl_up(ihi, d, 64);
            if (lane >= d) { ilo += ulo; ihi += uhi; }
        }
        unsigned long long tlo = __shfl(ilo, 63, 64), thi = __shfl(ihi, 63, 64);
        unsigned long long plo = ilo - clo, phi = ihi - chi;
        int mytot = 0;
        if (lane < 4) mytot = (int)((tlo >> (lane * 16)) & 0xffff);
        else if (lane < 8) mytot = (int)((thi >> ((lane - 4) * 16)) & 0xffff);
        int alloc = 0;
        if (lane < 8) alloc = atomicAdd(&bcur[lane], mytot);
#pragma unroll
        for (int j = 0; j < 16; j++) {
            int b = bins[j];
            int bs = (b < 0) ? 0 : b;
            int bbase = __shfl(alloc, bs, 64);
            int sh = (bs & 3) * 16;
            unsigned long long sel = (bs < 4) ? plo : phi;
            int rel = (int)((sel >> sh) & 0xffffu);
            unsigned long long inc = 1ull << sh;
            if (bs < 4) plo += inc; else phi += inc;
            if (b >= 0) binned[(size_t)bs * bin_cap + bbase + rel] = vals[j];
        }
    }
}

// ---------------- GEMM body (layer 1: A f32, 3-term, LDS-staged B): Hs = fp16(A@W1) ----------
__device__ __forceinline__ void gemm_body_f32(const float* __restrict__ A,
                                              const _Float16* __restrict__ whi,
                                              const _Float16* __restrict__ wlo,
                                              unsigned short* __restrict__ out, int M,
                                              int bid, int tid, uint4* __restrict__ sB) {
    int l = tid & 63;
    int w = tid >> 6;
    int r0 = bid * 64 + w * 16;
    int ra = r0 + (l & 15);
    if (ra >= M) ra = M - 1;
    int kl = (l >> 4) * 8;

    float4 af0[4], af1[4];
#pragma unroll
    for (int kt = 0; kt < 4; kt++) {
        const float* pa = A + (size_t)ra * 128 + kt * 32 + kl;
        af0[kt] = *(const float4*)pa;
        af1[kt] = *(const float4*)(pa + 4);
    }

    {
        const uint4* gh = (const uint4*)whi;
        const uint4* gl = (const uint4*)wlo;
#pragma unroll
        for (int i = 0; i < 8; i++) sB[tid + i * 256] = gh[tid + i * 256];
#pragma unroll
        for (int i = 0; i < 8; i++) sB[2048 + tid + i * 256] = gl[tid + i * 256];
    }
    __syncthreads();

    f32x4 acc[8];
#pragma unroll
    for (int i = 0; i < 8; i++) acc[i] = (f32x4)0.f;

    const half8* bh8 = (const half8*)sB;
    const half8* bl8 = (const half8*)(sB + 2048);

#pragma unroll
    for (int kt = 0; kt < 4; kt++) {
        half8 ah, al;
        float fa[8] = {af0[kt].x, af0[kt].y, af0[kt].z, af0[kt].w,
                       af1[kt].x, af1[kt].y, af1[kt].z, af1[kt].w};
#pragma unroll
        for (int j = 0; j < 8; j++) {
            _Float16 h = (_Float16)fa[j];
            ah[j] = h;
            al[j] = (_Float16)(fa[j] - (float)h);
        }
#pragma unroll
        for (int ct = 0; ct < 8; ct++) {
            half8 bh = bh8[(kt * 8 + ct) * 64 + l];
            half8 bl = bl8[(kt * 8 + ct) * 64 + l];
            acc[ct] = __builtin_amdgcn_mfma_f32_16x16x32_f16(ah, bh, acc[ct], 0, 0, 0);
            acc[ct] = __builtin_amdgcn_mfma_f32_16x16x32_f16(al, bh, acc[ct], 0, 0, 0);
            acc[ct] = __builtin_amdgcn_mfma_f32_16x16x32_f16(ah, bl, acc[ct], 0, 0, 0);
        }
    }

    __syncthreads();
    _Float16* stw = (_Float16*)sB + w * 2048;
#pragma unroll
    for (int r = 0; r < 4; r++) {
        int trow = (l >> 4) * 4 + r;
#pragma unroll
        for (int ct = 0; ct < 8; ct++)
            stw[trow * 128 + ct * 16 + (l & 15)] = (_Float16)(acc[ct][r]);
    }
#pragma unroll
    for (int p = 0; p < 4; p++) {
        int trow = p * 4 + (l >> 4);
        int grow = r0 + trow;
        if (grow < M) {
            uint4 v = *(const uint4*)&stw[trow * 128 + (l & 15) * 8];
            *(uint4*)&out[(size_t)grow * 128 + (l & 15) * 8] = v;
        }
    }
}

// Merged: blocks [0, bin_blocks) bin the edges; the rest run layer-1 GEMM (independent).
__global__ __launch_bounds__(256) void k_bingemm(const int* __restrict__ src, const int* __restrict__ dst,
                                                 int* __restrict__ bcur, unsigned int* __restrict__ binned,
                                                 int E, int mul, int bin_cap,
                                                 const float* __restrict__ x,
                                                 const _Float16* __restrict__ whi,
                                                 const _Float16* __restrict__ wlo,
                                                 unsigned short* __restrict__ outHs, int M, int bin_blocks) {
    __shared__ uint4 sB[4096];  // 64 KB (gemm path)
    if ((int)blockIdx.x < bin_blocks) {
        bin_body(src, dst, bcur, binned, E, mul, bin_cap, blockIdx.x, bin_blocks, threadIdx.x);
        return;
    }
    gemm_body_f32(x, whi, wlo, outHs, M, blockIdx.x - bin_blocks, threadIdx.x, sB);
}

// ---------------- Phase 2a: per-(bin,block) LDS histogram -> partial counts ----------------
__global__ __launch_bounds__(256) void k_count(const unsigned int* __restrict__ binned,
                                               const int* __restrict__ bcnt, int* __restrict__ phist,
                                               int mul, int bin_cap) {
    __shared__ int hist[HSZ];
    int b = blockIdx.x & 7;
    int blk = blockIdx.x >> 3;
    int t = threadIdx.x;
    for (int i = t; i < HSZ; i += 256) hist[i] = 0;
    __syncthreads();
    int lo = bin_lo(b, mul);
    int cnt = bcnt[b];
    int e0 = (int)((long long)blk * cnt / BPB);
    int e1 = (int)((long long)(blk + 1) * cnt / BPB);
    const unsigned int* bp = binned + (size_t)b * bin_cap;
    for (int i = e0 + t; i < e1; i += 256) {
        int d = (int)(bp[i] & 0xffffu);
        atomicAdd(&hist[d - lo], 1);
    }
    __syncthreads();
    int* ph = phist + (size_t)blockIdx.x * HSZ;
    for (int i = t; i < HSZ; i += 256) ph[i] = hist[i];
}

// ---------------- Phase 2b: deg from partials; partials -> exclusive prefixes; padded block sums ----
__global__ __launch_bounds__(256) void k_bsum(int* __restrict__ phist, int* __restrict__ deg,
                                              int* __restrict__ bsum, int N, int mul) {
    int t = threadIdx.x;
    int base = blockIdx.x * 1024;
    int s = 0;
    for (int j = 0; j < 4; j++) {
        int i = base + j * 256 + t;
        if (i < N) {
            int b = (i * mul) >> 25;
            int lo = bin_lo(b, mul);
            int local = i - lo;
            int run = 0;
#pragma unroll
            for (int blk = 0; blk < BPB; blk++) {
                int* p = phist + (size_t)(blk * 8 + b) * HSZ + local;
                int c = *p;
                *p = run;
                run += c;
            }
            deg[i] = run;
            s += (run + 7) & ~7;
        }
    }
#pragma unroll
    for (int d = 1; d < 64; d <<= 1) s += __shfl_xor(s, d, 64);
    __shared__ int ws[4];
    if ((t & 63) == 0) ws[t >> 6] = s;
    __syncthreads();
    if (t == 0) bsum[blockIdx.x] = ws[0] + ws[1] + ws[2] + ws[3];
}

// ---------------- scanout with inline top-scan: row_start (8-aligned), rend, dinv ----------------
__global__ __launch_bounds__(256) void k_scanout(const int* __restrict__ deg, const int* __restrict__ bsum,
                                                 int* __restrict__ row_start, int* __restrict__ rend,
                                                 float* __restrict__ dinv, int n, int nb) {
    __shared__ int s_boff;
    __shared__ int ws[4];
    int t = threadIdx.x, lane = t & 63, wid = t >> 6;
    if (t < 64) {
        int v = (t < nb) ? bsum[t] : 0;
        int incl = v;
#pragma unroll
        for (int d = 1; d < 64; d <<= 1) {
            int u = __shfl_up(incl, d, 64);
            if (t >= d) incl += u;
        }
        if (t == (int)blockIdx.x) s_boff = incl - v;
    }
    __syncthreads();
    int base = blockIdx.x * 1024 + t * 4;
    int v[4], pv[4], ts = 0;
#pragma unroll
    for (int j = 0; j < 4; j++) {
        v[j] = (base + j < n) ? deg[base + j] : 0;
        pv[j] = (v[j] + 7) & ~7;
        ts += pv[j];
    }
    int incl = ts;
#pragma unroll
    for (int d = 1; d < 64; d <<= 1) {
        int u = __shfl_up(incl, d, 64);
        if (lane >= d) incl += u;
    }
    if (lane == 63) ws[wid] = incl;
    __syncthreads();
    int wo = 0;
    for (int i = 0; i < wid; i++) wo += ws[i];
    int run = s_boff + wo + (incl - ts);
#pragma unroll
    for (int j = 0; j < 4; j++) {
        if (base + j < n) {
            row_start[base + j] = run;
            rend[base + j] = run + v[j];
            dinv[base + j] = rsqrtf((float)v[j] + 1.0f);
            run += pv[j];
        }
    }
}

// ---------------- Phase 2c: fill via LDS cursors; csr entry = (fp16(dinv[src])<<16) | src ----------
__global__ __launch_bounds__(256) void k_fill(const unsigned int* __restrict__ binned,
                                              const int* __restrict__ bcnt, const int* __restrict__ row_start,
                                              const int* __restrict__ phist, const float* __restrict__ dinv,
                                              unsigned int* __restrict__ csr,
                                              int N, int mul, int bin_cap) {
    __shared__ int cur[HSZ];
    int b = blockIdx.x & 7;
    int blk = blockIdx.x >> 3;
    int t = threadIdx.x;
    int lo = bin_lo(b, mul);
    int hi = (b == 7) ? N : bin_lo(b + 1, mul);
    if (hi > N) hi = N;
    const int* ph = phist + (size_t)blockIdx.x * HSZ;
    for (int i = t; i < HSZ; i += 256) {
        int d = lo + i;
        cur[i] = (d < hi) ? (row_start[d] + ph[i]) : 0;
    }
    __syncthreads();
    int cnt = bcnt[b];
    int e0 = (int)((long long)blk * cnt / BPB);
    int e1 = (int)((long long)(blk + 1) * cnt / BPB);
    const unsigned int* bp = binned + (size_t)b * bin_cap;
    for (int i = e0 + t; i < e1; i += 256) {
        unsigned int v = bp[i];
        int d = (int)(v & 0xffffu);
        int s = (int)(v >> 16);
        __half h = __float2half_rn(dinv[s]);
        unsigned short hb = *(unsigned short*)&h;
        int q = atomicAdd(&cur[d - lo], 1);   // LDS atomic
        csr[q] = ((unsigned int)hb << 16) | (unsigned int)s;
    }
}

// ---------------- weighted fp16 gather helpers ----------------
__device__ __forceinline__ void f2fma(float2& a, const __half2 h, float w) {
    float2 f = __half22float2(h);
    a.x = fmaf(f.x, w, a.x);
    a.y = fmaf(f.y, w, a.y);
}

__device__ __forceinline__ float pk_w(unsigned int pk) {
    __half h;
    *(unsigned short*)&h = (unsigned short)(pk >> 16);
    return __half2float(h);
}

// single-chunk pipeline (8 gathers in flight) — lower VGPR for the fused kernel
__device__ __forceinline__ void aggr_gather1(const float4* __restrict__ Hs4, const unsigned int* __restrict__ csr,
                                             int rs, int re, int node, float dn, int lc, float2 acc[4]) {
    {
        float4 sv = Hs4[(size_t)node * 16 + lc];
        const __half2* h = (const __half2*)&sv;
        float2 f0 = __half22float2(h[0]), f1 = __half22float2(h[1]);
        float2 f2 = __half22float2(h[2]), f3 = __half22float2(h[3]);
        acc[0] = make_float2(f0.x * dn, f0.y * dn);
        acc[1] = make_float2(f1.x * dn, f1.y * dn);
        acc[2] = make_float2(f2.x * dn, f2.y * dn);
        acc[3] = make_float2(f3.x * dn, f3.y * dn);
    }
    int nch = (re - rs + 7) >> 3;
    if (nch <= 0) return;
    float2 accB[4] = {{0.f, 0.f}, {0.f, 0.f}, {0.f, 0.f}, {0.f, 0.f}};
    const uint4* cp = (const uint4*)(csr + rs);
    uint4 q0 = cp[0], q1 = cp[1];
    for (int c = 0; c < nch; c++) {
        uint4 n0 = q0, n1 = q1;
        if (c + 1 < nch) { n0 = cp[2 * c + 2]; n1 = cp[2 * c + 3]; }
        unsigned int pks[8] = {q0.x, q0.y, q0.z, q0.w, q1.x, q1.y, q1.z, q1.w};
        int base = rs + c * 8;
        float4 v[8];
        float w[8];
#pragma unroll
        for (int j = 0; j < 8; j++) {
            unsigned int pk = (base + j < re) ? pks[j] : 0u;
            w[j] = pk_w(pk);
            v[j] = Hs4[(size_t)(pk & 0xffffu) * 16 + lc];
        }
#pragma unroll
        for (int j = 0; j < 8; j++) {
            const __half2* h = (const __half2*)&v[j];
            float2* acp = (j & 1) ? accB : acc;
            f2fma(acp[0], h[0], w[j]);
            f2fma(acp[1], h[1], w[j]);
            f2fma(acp[2], h[2], w[j]);
            f2fma(acp[3], h[3], w[j]);
        }
        q0 = n0; q1 = n1;
    }
#pragma unroll
    for (int k = 0; k < 4; k++) {
        acc[k].x += accB[k].x;
        acc[k].y += accB[k].y;
    }
}

__device__ __forceinline__ void bn_relu(const float2 acc[4], float dn, const float* __restrict__ par,
                                        int lc, float4& y0, float4& y1) {
    float4 s0 = ((const float4*)par)[lc * 2];
    float4 s1 = ((const float4*)par)[lc * 2 + 1];
    float4 t0 = ((const float4*)par)[32 + lc * 2];
    float4 t1 = ((const float4*)par)[32 + lc * 2 + 1];
    y0.x = fmaxf(fmaf(acc[0].x * dn, s0.x, t0.x), 0.f);
    y0.y = fmaxf(fmaf(acc[0].y * dn, s0.y, t0.y), 0.f);
    y0.z = fmaxf(fmaf(acc[1].x * dn, s0.z, t0.z), 0.f);
    y0.w = fmaxf(fmaf(acc[1].y * dn, s0.w, t0.w), 0.f);
    y1.x = fmaxf(fmaf(acc[2].x * dn, s1.x, t1.x), 0.f);
    y1.y = fmaxf(fmaf(acc[2].y * dn, s1.y, t1.y), 0.f);
    y1.z = fmaxf(fmaf(acc[3].x * dn, s1.z, t1.z), 0.f);
    y1.w = fmaxf(fmaf(acc[3].y * dn, s1.w, t1.w), 0.f);
}

// ---------------- FUSED: layer-1 aggregation + layer-2 GEMM (one block = 32 nodes) -------------
// 512-thread blocks (8 waves): tests the big-workgroup occupancy limit seen at 1024 threads.
// LDS = 32 KB (whi frags) + 8 KB (A in MFMA-fragment layout; reused for C) = 40 KB
// -> up to 4 blocks/CU (threads 2048/512; LDS 160/40). wlo read from global (L2-resident).
__global__ __launch_bounds__(512, 4) void k_aggr_gemm(const float4* __restrict__ Hs4,
                                                      const int* __restrict__ row_start,
                                                      const int* __restrict__ rend,
                                                      const unsigned int* __restrict__ csr,
                                                      const float* __restrict__ dinv,
                                                      const float* __restrict__ par,
                                                      const _Float16* __restrict__ whi,
                                                      const _Float16* __restrict__ wlo,
                                                      unsigned short* __restrict__ outHs2, int n) {
    __shared__ uint4 sB[2048];            // 32 KB: whi fragment image
    __shared__ _Float16 sA[32 * 128];     // 8 KB: A in fragment layout (reused for C)
    int t = threadIdx.x;

    // stage whi early (latency overlaps the gather below): 4 uint4 per thread
    {
        const uint4* gh = (const uint4*)whi;
        sB[t] = gh[t];
        sB[t + 512] = gh[t + 512];
        sB[t + 1024] = gh[t + 1024];
        sB[t + 1536] = gh[t + 1536];
    }

    int lc = t & 15;
    int nl = t >> 4;                      // local node 0..31
    int node = blockIdx.x * 32 + nl;
    float4 y0 = make_float4(0.f, 0.f, 0.f, 0.f);
    float4 y1 = make_float4(0.f, 0.f, 0.f, 0.f);
    if (node < n) {
        float dn = dinv[node];
        float2 acc[4];
        aggr_gather1(Hs4, csr, row_start[node], rend[node], node, dn, lc, acc);
        bn_relu(acc, dn, par, lc, y0, y1);
    }
    // write A directly in MFMA fragment layout: rt = nl>>4 (0..1), kt = lc>>2
    {
        half8 av;
        av[0] = (_Float16)y0.x; av[1] = (_Float16)y0.y; av[2] = (_Float16)y0.z; av[3] = (_Float16)y0.w;
        av[4] = (_Float16)y1.x; av[5] = (_Float16)y1.y; av[6] = (_Float16)y1.z; av[7] = (_Float16)y1.w;
        int tile = ((nl >> 4) << 2) | (lc >> 2);   // rt*4 + kt, 0..7
        int fl = ((lc & 3) << 4) | (nl & 15);
        ((half8*)sA)[tile * 64 + fl] = av;
    }
    __syncthreads();

    // GEMM: 16 output tiles (tile = rt*8+ct; rt in [0,2), ct in [0,8)); wave w -> tiles 2w, 2w+1
    int w = t >> 6, l = t & 63;
    const half8* bh8 = (const half8*)sB;
    const half8* gl8 = (const half8*)wlo;   // global (L2-resident)
    const half8* aF = (const half8*)sA;
    f32x4 accT[2];
#pragma unroll
    for (int tt = 0; tt < 2; tt++) {
        int tile = w * 2 + tt;
        int rt = tile >> 3, ct = tile & 7;
        half8 bl[4];
#pragma unroll
        for (int kt = 0; kt < 4; kt++) bl[kt] = gl8[(kt * 8 + ct) * 64 + l];
        f32x4 acc = (f32x4)0.f;
#pragma unroll
        for (int kt = 0; kt < 4; kt++) {
            half8 a = aF[(rt * 4 + kt) * 64 + l];
            half8 bh = bh8[(kt * 8 + ct) * 64 + l];
            acc = __builtin_amdgcn_mfma_f32_16x16x32_f16(a, bh, acc, 0, 0, 0);
            acc = __builtin_amdgcn_mfma_f32_16x16x32_f16(a, bl[kt], acc, 0, 0, 0);
        }
        accT[tt] = acc;
    }
    __syncthreads();  // all A reads done; reuse sA for C (flat [32][128])

#pragma unroll
    for (int tt = 0; tt < 2; tt++) {
        int tile = w * 2 + tt;
        int rt = tile >> 3, ct = tile & 7;
#pragma unroll
        for (int r = 0; r < 4; r++) {
            int row = rt * 16 + (l >> 4) * 4 + r;
            sA[row * 128 + ct * 16 + (l & 15)] = (_Float16)(accT[tt][r]);
        }
    }
    __syncthreads();

    // coalesced store: thread t -> row t>>4 (0..31), 8 channels at (t&15)*8
    {
        int row = t >> 4;
        int grow = blockIdx.x * 32 + row;
        if (grow < n) {
            uint4 v = *(const uint4*)&sA[row * 128 + (t & 15) * 8];
            *(uint4*)&outHs2[(size_t)grow * 128 + (t & 15) * 8] = v;
        }
    }
}

// ---------------- layer-2 aggregation + classifier (2-chunk pipeline gather) ----------------
__device__ __forceinline__ void aggr_gather2(const float4* __restrict__ Hs4, const unsigned int* __restrict__ csr,
                                             int rs, int re, int node, float dn, int lc, float2 acc[4]) {
    {
        float4 sv = Hs4[(size_t)node * 16 + lc];
        const __half2* h = (const __half2*)&sv;
        float2 f0 = __half22float2(h[0]), f1 = __half22float2(h[1]);
        float2 f2 = __half22float2(h[2]), f3 = __half22float2(h[3]);
        acc[0] = make_float2(f0.x * dn, f0.y * dn);
        acc[1] = make_float2(f1.x * dn, f1.y * dn);
        acc[2] = make_float2(f2.x * dn, f2.y * dn);
        acc[3] = make_float2(f3.x * dn, f3.y * dn);
    }
    int nch = (re - rs + 7) >> 3;
    if (nch <= 0) return;
    float2 accB[4] = {{0.f, 0.f}, {0.f, 0.f}, {0.f, 0.f}, {0.f, 0.f}};
    const uint4* cp = (const uint4*)(csr + rs);
    uint4 qa0 = cp[0], qa1 = cp[1];
    uint4 qb0 = cp[2], qb1 = cp[3];
    for (int c = 0; c < nch; c += 2) {
        uint4 na0 = qa0, na1 = qa1, nb0 = qb0, nb1 = qb1;
        if (c + 2 < nch) { na0 = cp[2 * c + 4]; na1 = cp[2 * c + 5]; nb0 = cp[2 * c + 6]; nb1 = cp[2 * c + 7]; }
        unsigned int pA[8] = {qa0.x, qa0.y, qa0.z, qa0.w, qa1.x, qa1.y, qa1.z, qa1.w};
        unsigned int pB[8] = {qb0.x, qb0.y, qb0.z, qb0.w, qb1.x, qb1.y, qb1.z, qb1.w};
        int baseA = rs + c * 8;
        int baseB = baseA + 8;
        float4 vA[8], vB[8];
        float wA[8], wB[8];
#pragma unroll
        for (int j = 0; j < 8; j++) {
            unsigned int pk = (baseA + j < re) ? pA[j] : 0u;
            wA[j] = pk_w(pk);
            vA[j] = Hs4[(size_t)(pk & 0xffffu) * 16 + lc];
        }
#pragma unroll
        for (int j = 0; j < 8; j++) {
            unsigned int pk = (baseB + j < re) ? pB[j] : 0u;
            wB[j] = pk_w(pk);
            vB[j] = Hs4[(size_t)(pk & 0xffffu) * 16 + lc];
        }
#pragma unroll
        for (int j = 0; j < 8; j++) {
            const __half2* h = (const __half2*)&vA[j];
            float2* acp = (j & 1) ? accB : acc;
            f2fma(acp[0], h[0], wA[j]);
            f2fma(acp[1], h[1], wA[j]);
            f2fma(acp[2], h[2], wA[j]);
            f2fma(acp[3], h[3], wA[j]);
        }
#pragma unroll
        for (int j = 0; j < 8; j++) {
            const __half2* h = (const __half2*)&vB[j];
            float2* acp = (j & 1) ? accB : acc;
            f2fma(acp[0], h[0], wB[j]);
            f2fma(acp[1], h[1], wB[j]);
            f2fma(acp[2], h[2], wB[j]);
            f2fma(acp[3], h[3], wB[j]);
        }
        qa0 = na0; qa1 = na1; qb0 = nb0; qb1 = nb1;
    }
#pragma unroll
    for (int k = 0; k < 4; k++) {
        acc[k].x += accB[k].x;
        acc[k].y += accB[k].y;
    }
}

__global__ __launch_bounds__(256) void k_aggr_cls(const float4* __restrict__ Hs4, const int* __restrict__ row_start,
                                                  const int* __restrict__ rend,
                                                  const unsigned int* __restrict__ csr, const float* __restrict__ dinv,
                                                  const float* __restrict__ par, const float4* __restrict__ Wc4,
                                                  const float* __restrict__ bc, float2* __restrict__ out, int n) {
    int lc = threadIdx.x & 15;
    int node = blockIdx.x * 16 + (threadIdx.x >> 4);
    if (node >= n) return;
    float dn = dinv[node];
    float2 acc[4];
    aggr_gather2(Hs4, csr, row_start[node], rend[node], node, dn, lc, acc);
    float4 y0, y1;
    bn_relu(acc, dn, par, lc, y0, y1);
    float4 w0 = Wc4[lc * 4], w1 = Wc4[lc * 4 + 1], w2 = Wc4[lc * 4 + 2], w3 = Wc4[lc * 4 + 3];
    float p0 = y0.x * w0.x + y0.y * w0.z + y0.z * w1.x + y0.w * w1.z
             + y1.x * w2.x + y1.y * w2.z + y1.z * w3.x + y1.w * w3.z;
    float p1 = y0.x * w0.y + y0.y * w0.w + y0.z * w1.y + y0.w * w1.w
             + y1.x * w2.y + y1.y * w2.w + y1.z * w3.y + y1.w * w3.w;
#pragma unroll
    for (int d = 1; d < 16; d <<= 1) {
        p0 += __shfl_xor(p0, d, 16);
        p1 += __shfl_xor(p1, d, 16);
    }
    if (lc == 0) out[node] = make_float2(p0 + bc[0], p1 + bc[1]);
}

extern "C" void kernel_launch(void* const* d_in, const int* in_sizes, int n_in,
                              void* d_out, int out_size, void* d_ws, size_t ws_size,
                              hipStream_t stream) {
    const float* x = (const float*)d_in[0];
    const int* ei = (const int*)d_in[1];
    const float* W1 = (const float*)d_in[2];
    const float* b1 = (const float*)d_in[3];
    const float* g1 = (const float*)d_in[4];
    const float* be1 = (const float*)d_in[5];
    const float* m1 = (const float*)d_in[6];
    const float* v1 = (const float*)d_in[7];
    const float* W2 = (const float*)d_in[8];
    const float* b2 = (const float*)d_in[9];
    const float* g2 = (const float*)d_in[10];
    const float* be2 = (const float*)d_in[11];
    const float* m2 = (const float*)d_in[12];
    const float* v2 = (const float*)d_in[13];
    const float* Wc = (const float*)d_in[14];
    const float* bc = (const float*)d_in[15];
    float* out = (float*)d_out;

    const int N = in_sizes[0] / 128;   // 50000 (< 65536: u16 packing valid; N/8 < HSZ)
    const int E = in_sizes[1] / 2;
    const int* src = ei;
    const int* dst = ei + E;

    const int mul = (int)((8LL << 25) / N);
    const int bin_cap = ((E / 8 + 8192 + 63) / 64) * 64;

    // workspace layout (int units)
    int* W = (int*)d_ws;
    size_t off = 0;
    int* deg = W + off; off += N;
    int* bcur = W + off; off += 8;
    int* row_start = W + off; off += (size_t)N + 1;
    int* rend = W + off; off += N;
    float* dinv = (float*)(W + off); off += N;
    int* bsum = W + off; off += 64;
    float* par = (float*)(W + off); off += 512;
    _Float16* whi1 = (_Float16*)(W + off); off += 8192;   // 16384 halves (32 KB)
    _Float16* wlo1 = (_Float16*)(W + off); off += 8192;
    _Float16* whi2 = (_Float16*)(W + off); off += 8192;
    _Float16* wlo2 = (_Float16*)(W + off); off += 8192;
    int* phist = W + off; off += (size_t)8 * BPB * HSZ;   // 6.5 MB (fully overwritten each call)
    unsigned int* csr = (unsigned int*)(W + off); off += (size_t)E + 8 * N + 64;  // u32 entries
    unsigned int* binned = (unsigned int*)(W + off); off += (size_t)8 * bin_cap;
    off = (off + 3) & ~(size_t)3;
    __half* Hs = (__half*)(W + off); off += (size_t)N * 64;    // N*128 halves (layer-1 GEMM out)
    __half* Hs2 = (__half*)(W + off);                          // N*128 halves (fused out)

    // setup: W frag split x2 + BN consts + zero bcur
    k_setup<<<33, 128, 0, stream>>>(W1, W2, whi1, wlo1, whi2, wlo2,
                                    g1, v1, b1, m1, be1, g2, v2, b2, m2, be2,
                                    par, bcur);

    int nb = (N + 1023) / 1024;  // <= 64
    int gbm = (N + 63) / 64;
    int bin_blocks = 512;
    // merged: edge binning overlapped with layer-1 GEMM
    k_bingemm<<<bin_blocks + gbm, 256, 0, stream>>>(src, dst, bcur, binned, E, mul, bin_cap,
                                                    x, whi1, wlo1, (unsigned short*)Hs, N, bin_blocks);
    k_count<<<8 * BPB, 256, 0, stream>>>(binned, bcur, phist, mul, bin_cap);
    k_bsum<<<nb, 256, 0, stream>>>(phist, deg, bsum, N, mul);
    k_scanout<<<nb, 256, 0, stream>>>(deg, bsum, row_start, rend, dinv, N, nb);
    k_fill<<<8 * BPB, 256, 0, stream>>>(binned, bcur, row_start, phist, dinv, csr, N, mul, bin_cap);

    // fused: layer-1 aggregation + BN/ReLU + layer-2 GEMM -> Hs2 (512-thread blocks, 32 nodes)
    int gba = (N + 31) / 32;
    k_aggr_gemm<<<gba, 512, 0, stream>>>((const float4*)Hs, row_start, rend, csr, dinv, par,
                                         whi2, wlo2, (unsigned short*)Hs2, N);
    // layer-2 aggregation + BN/ReLU + classifier
    int ab = (N + 15) / 16;
    k_aggr_cls<<<ab, 256, 0, stream>>>((const float4*)Hs2, row_start, rend, csr, dinv, par + 256,
                                       (const float4*)Wc, bc, (float2*)out, N);
}